// Round 5
// baseline (203.289 us; speedup 1.0000x reference)
//
#include <hip/hip_runtime.h>
#include <cstddef>

#define SSM_N 64
#define SSM_H 256
#define SSM_B 8
#define SSM_L 1024
#define PADB  68    // LDS row stride (floats); 272B rows, 16B-aligned
#define KTP   1040  // K_T row stride in floats

// ---------- prep helpers ----------

// lane's full row r of a 64x64 LDS matrix into 64 regs (16 x b128; 8-way bank
// alias tolerated: 16 reads/matmul only)
__device__ __forceinline__ void load_row(const float* M, int r, float (&arow)[64])
{
    #pragma unroll
    for (int q = 0; q < 16; ++q) {
        const float4 v = *reinterpret_cast<const float4*>(M + r * PADB + 4 * q);
        arow[4*q+0] = v.x; arow[4*q+1] = v.y; arow[4*q+2] = v.z; arow[4*q+3] = v.w;
    }
}

// acc[0..7] += arow[t] * B[t][g8 .. g8+7].  B reads are wave-uniform float4
// broadcasts (g8 constant per wave) -> conflict-free, ~16B/instr.
__device__ __forceinline__ void mm_row8(const float (&arow)[64], const float* B,
                                        int g8, float (&acc)[8])
{
    #pragma unroll
    for (int t = 0; t < 64; ++t) {
        const float4 b0 = *reinterpret_cast<const float4*>(B + t * PADB + g8);
        const float4 b1 = *reinterpret_cast<const float4*>(B + t * PADB + g8 + 4);
        const float a = arow[t];
        acc[0] += a * b0.x; acc[1] += a * b0.y; acc[2] += a * b0.z; acc[3] += a * b0.w;
        acc[4] += a * b1.x; acc[5] += a * b1.y; acc[6] += a * b1.z; acc[7] += a * b1.w;
    }
}

// One block per channel h. 512 threads = 8 waves; lane r = tid&63 owns row r,
// wave w = tid>>6 owns cols [8w, 8w+8). Doubling ladder E_k = Ab^(2^k), k=0..9;
// c_j = C*Ab^j (j<32) and x_m = Ab^(32m)*Bb (m<32) by log-doubling, with the
// 2^k independent vec-mats of stage k spread across waves.
__global__ __launch_bounds__(512) void ssm_prep_kernel(
    const float* __restrict__ As, const float* __restrict__ Bsin,
    const float* __restrict__ Csin, const float* __restrict__ logsteps,
    float* __restrict__ KTout)
{
    __shared__ __align__(16) float Ea[SSM_N * PADB];
    __shared__ __align__(16) float Eb[SSM_N * PADB];
    __shared__ __align__(16) float Cm[32 * PADB];
    __shared__ __align__(16) float Xm[32 * PADB];
    __shared__ float bvs[64];

    const int h   = blockIdx.x;
    const int tid = threadIdx.x;
    const int r   = tid & 63;
    const int w   = tid >> 6;
    const int g8  = w * 8;

    const float step = expf(logsteps[h]);
    const float s    = 0.5f * step;

    // ---- stage M = s*A (coalesced float4), Cs -> Cm row 0, b -> bvs ----
    #pragma unroll
    for (int ps = 0; ps < 2; ++ps) {
        const float4 v = *reinterpret_cast<const float4*>(
            As + (size_t)h * 4096 + 2048 * ps + 4 * tid);
        const int row = 32 * ps + (tid >> 4);
        const int col = (tid & 15) * 4;
        *reinterpret_cast<float4*>(Ea + row * PADB + col) =
            make_float4(s * v.x, s * v.y, s * v.z, s * v.w);
    }
    if (tid < 64)       Cm[tid]        = Csin[h * SSM_N + tid];
    else if (tid < 128) bvs[tid - 64]  = Bsin[h * SSM_N + tid - 64];
    __syncthreads();

    float arow[64];
    load_row(Ea, r, arow);                 // M row r (reused for both Neumann mms)
    float acc[8];

    // ---- T = M*M + M -> Eb ----
    #pragma unroll
    for (int j = 0; j < 8; ++j) acc[j] = arow[g8 + j];
    mm_row8(arow, Ea, g8, acc);
    *reinterpret_cast<float4*>(Eb + r * PADB + g8)     = make_float4(acc[0], acc[1], acc[2], acc[3]);
    *reinterpret_cast<float4*>(Eb + r * PADB + g8 + 4) = make_float4(acc[4], acc[5], acc[6], acc[7]);
    __syncthreads();

    // ---- S = M*T + M ; E0 = I + 2S -> Ea (no one reads Ea during this mm) ----
    #pragma unroll
    for (int j = 0; j < 8; ++j) acc[j] = arow[g8 + j];
    mm_row8(arow, Eb, g8, acc);
    #pragma unroll
    for (int j = 0; j < 8; ++j)
        Ea[r * PADB + g8 + j] = 2.f * acc[j] + ((r == g8 + j) ? 1.f : 0.f);
    __syncthreads();

    // ---- ladder k = 0..9 ----
    float* Ecur = Ea;
    float* Enxt = Eb;
    #pragma unroll 1
    for (int k = 0; k < 10; ++k) {
        load_row(Ecur, r, arow);           // E_k row r

        if (k == 0 && w == 0) {
            // x0 = Bb = s*(b + E0 b): lane r uses its E0 row (= arow)
            float a = 0.f;
            #pragma unroll
            for (int t = 0; t < 64; ++t) a += arow[t] * bvs[t];
            Xm[r] = s * (bvs[r] + a);
        }

        if (k <= 4) {
            // c-stage: c_{j+2^k} = c_j * E_k  (lane = output column r)
            const int nj = 1 << k;
            #pragma unroll
            for (int rep = 0; rep < 2; ++rep) {
                const int j = w + 8 * rep;
                if (j < nj) {
                    const float* crow = Cm + j * PADB;
                    float a = 0.f;
                    #pragma unroll
                    for (int t = 0; t < 64; ++t)
                        a += crow[t] * Ecur[t * PADB + r];   // bcast * lane-contig
                    Cm[(j + nj) * PADB + r] = a;
                }
            }
        } else {
            // x-stage: x_{m+2^kx} = E_{5+kx} x_m  (lane = output row r, uses arow)
            const int kx = k - 5;
            const int nm = 1 << kx;
            #pragma unroll
            for (int rep = 0; rep < 2; ++rep) {
                const int m = w + 8 * rep;
                if (m < nm) {
                    const float* xs = Xm + m * PADB;
                    float a = 0.f;
                    #pragma unroll
                    for (int t = 0; t < 64; ++t)
                        a += arow[t] * xs[t];                // reg * bcast
                    Xm[(m + nm) * PADB + r] = a;
                }
            }
        }

        if (k < 9) {
            // E_{k+1} = E_k^2 -> Enxt
            #pragma unroll
            for (int j = 0; j < 8; ++j) acc[j] = 0.f;
            mm_row8(arow, Ecur, g8, acc);
            *reinterpret_cast<float4*>(Enxt + r * PADB + g8)     = make_float4(acc[0], acc[1], acc[2], acc[3]);
            *reinterpret_cast<float4*>(Enxt + r * PADB + g8 + 4) = make_float4(acc[4], acc[5], acc[6], acc[7]);
        }
        __syncthreads();
        float* tmp = Ecur; Ecur = Enxt; Enxt = tmp;
    }

    // ---- KT[h][32m + j] = dot(c_j, x_m)  (coalesced contiguous write) ----
    #pragma unroll
    for (int rep = 0; rep < 2; ++rep) {
        const int l = tid + 512 * rep;
        const int m = l >> 5, j = l & 31;
        const float4* cr = reinterpret_cast<const float4*>(Cm + j * PADB);
        const float4* xr = reinterpret_cast<const float4*>(Xm + m * PADB);
        float d = 0.f;
        #pragma unroll
        for (int i = 0; i < 16; ++i) {
            const float4 c4 = cr[i], x4 = xr[i];
            d += c4.x * x4.x + c4.y * x4.y + c4.z * x4.z + c4.w * x4.w;
        }
        KTout[(size_t)h * KTP + l] = d;
    }
}

// ---------- KT (H x KTP) -> K (L x H), 32x32 LDS tiles ----------
__global__ __launch_bounds__(256) void ssm_ktr_kernel(
    const float* __restrict__ KT, float* __restrict__ K)
{
    __shared__ float tile[32][33];
    const int l0 = (blockIdx.x & 31) * 32;
    const int h0 = (blockIdx.x >> 5) * 32;
    const int c  = threadIdx.x & 31;
    const int r0 = threadIdx.x >> 5;
    #pragma unroll
    for (int k = 0; k < 4; ++k)
        tile[r0 + 8 * k][c] = KT[(size_t)(h0 + r0 + 8 * k) * KTP + l0 + c];
    __syncthreads();
    #pragma unroll
    for (int k = 0; k < 4; ++k)
        K[(size_t)(l0 + r0 + 8 * k) * SSM_H + h0 + c] = tile[c][r0 + 8 * k];
}

// ---------- conv helpers ----------

__device__ __forceinline__ void ld8(float (&d)[8], const float* base)
{
    #pragma unroll
    for (int j = 0; j < 8; ++j) d[j] = base[j * SSM_H];
}

// acc[i] += K[dd] * W[7+i-dd], W = cur[0..7] ++ prv[0..6]
__device__ __forceinline__ void fma8(float (&acc)[8], const float (&kv)[8],
                                     const float (&cur)[8], const float (&prv)[8])
{
    #pragma unroll
    for (int dd = 0; dd < 8; ++dd) {
        const float k = kv[dd];
        #pragma unroll
        for (int i = 0; i < 8; ++i) {
            const int idx = 7 + i - dd;
            const float u = (idx < 8) ? cur[idx] : prv[idx - 8];
            acc[i] += k * u;
        }
    }
}

// Causal conv: y[b,l,h] = sum_d K[d,h]*u[b,l-d,h] + Ds[h]*u[b,l,h].
// thread = h (coalesced). Block (b, p): 8-row tiles t = p and 127-p -> uniform
// 129 chunks. Clean loop unrolled x3 with rotating reg buffers: no copy-movs,
// loads land in fresh regs each chunk (pipelined waits). Guard-free steady state.
__global__ __launch_bounds__(256) void ssm_conv_kernel(
    const float* __restrict__ U, const float* __restrict__ Kk,
    const float* __restrict__ Ds, float* __restrict__ Y)
{
    const int h = threadIdx.x;
    const int b = blockIdx.x & 7;            // XCD-pinned batch slice
    const int p = blockIdx.x >> 3;           // 0..63
    const float dh = Ds[h];
    const float* Ub = U + (size_t)b * SSM_L * SSM_H + h;
    float* Yb = Y + (size_t)b * SSM_L * SSM_H + h;

    #pragma unroll
    for (int half = 0; half < 2; ++half) {
        const int t  = half ? (127 - p) : p;
        const int l0 = t << 3;

        float acc[8];
        #pragma unroll
        for (int i = 0; i < 8; ++i) acc[i] = 0.f;

        // canonical state: K-cur = kA; window W = wA[0..7] ++ wB[0..6]
        float kA[8], wA[8], wB[8];
        if (t == 0) {
            #pragma unroll
            for (int j = 0; j < 8; ++j) wA[j] = 0.f;
            wA[7] = Ub[0];
        } else {
            #pragma unroll
            for (int j = 0; j < 8; ++j) wA[j] = Ub[(l0 - 7 + j) * SSM_H];
        }
        #pragma unroll
        for (int j = 0; j < 7; ++j) wB[j] = Ub[(l0 + 1 + j) * SSM_H];  // <=1023 always
        wB[7] = 0.f;
        ld8(kA, Kk + h);                                   // K[0..7]

        const int nclean = (t >= 1) ? (t - 1) : 0;
        const int n3 = nclean - (nclean % 3);
        const float* kp = Kk + 8 * SSM_H + h;              // K[8(c+1)+j]
        const float* up = Ub + (ptrdiff_t)(l0 - 15) * SSM_H; // u[l0-8c-15+j]

        int c = 0;
        #pragma unroll 1
        for (; c < n3; c += 3) {
            float kB[8], kC[8], wC[8];
            // chunk c+0: loads feed c+1
            ld8(kB, kp);
            ld8(wC, up);
            fma8(acc, kA, wA, wB);                         // wB dies
            // chunk c+1
            ld8(kC, kp + 8 * SSM_H);
            ld8(wB, up - 8 * SSM_H);
            fma8(acc, kB, wC, wA);                         // wA dies
            // chunk c+2
            ld8(kA, kp + 16 * SSM_H);
            ld8(wA, up - 16 * SSM_H);
            fma8(acc, kC, wB, wC);                         // wC dies
            kp += 24 * SSM_H;
            up -= 24 * SSM_H;
        }
        // remainder clean chunks (0..2), generic copy-style
        #pragma unroll 1
        for (; c < nclean; ++c) {
            float kn[8], nw[8];
            ld8(kn, kp);
            ld8(nw, up);
            fma8(acc, kA, wA, wB);
            #pragma unroll
            for (int j = 0; j < 8; ++j) { wB[j] = wA[j]; wA[j] = nw[j]; kA[j] = kn[j]; }
            kp += 8 * SSM_H;
            up -= 8 * SSM_H;
        }

        if (t >= 1) {
            // boundary chunk c = t-1 (next window is zeros except u[0])
            float kn[8];
            #pragma unroll
            for (int j = 0; j < 8; ++j) kn[j] = Kk[(8 * t + j) * SSM_H + h];
            const float uz = Ub[0];
            fma8(acc, kA, wA, wB);
            // final chunk c = t: W = {0,..,0,uz} ++ wA[0..6]; skip zero terms
            #pragma unroll
            for (int dd = 0; dd < 8; ++dd) {
                const float k = kn[dd];
                #pragma unroll
                for (int i = 0; i < 8; ++i) {
                    const int idx = 7 + i - dd;
                    if (idx == 7)      acc[i] += k * uz;
                    else if (idx > 7)  acc[i] += k * wA[idx - 8];
                }
            }
        } else {
            // t == 0: single (final) chunk
            fma8(acc, kA, wA, wB);
        }

        #pragma unroll
        for (int i = 0; i < 8; ++i)
            Yb[(l0 + i) * SSM_H] = acc[i] + dh * Ub[(l0 + i) * SSM_H];
    }
}

extern "C" void kernel_launch(void* const* d_in, const int* in_sizes, int n_in,
                              void* d_out, int out_size, void* d_ws, size_t ws_size,
                              hipStream_t stream)
{
    const float* inp    = (const float*)d_in[0];  // (B,L,H)
    const float* As     = (const float*)d_in[1];  // (H,N,N)
    const float* Bsin   = (const float*)d_in[2];  // (H,N,1)
    const float* Csin   = (const float*)d_in[3];  // (H,1,N)
    const float* Dsin   = (const float*)d_in[4];  // (H,)
    const float* lsteps = (const float*)d_in[5];  // (H,)
    float* Y    = (float*)d_out;                  // (B,L,H)
    // KT staged in d_out head (consumed by ktr before conv overwrites with Y);
    // K (L,H) in 1MB of d_ws.
    float* KT   = (float*)d_out;
    float* Kbuf = (float*)d_ws;

    ssm_prep_kernel<<<dim3(SSM_H), dim3(512), 0, stream>>>(As, Bsin, Csin, lsteps, KT);
    ssm_ktr_kernel<<<dim3(256), dim3(256), 0, stream>>>(KT, Kbuf);
    ssm_conv_kernel<<<dim3(512), dim3(256), 0, stream>>>(inp, Kbuf, Dsin, Y);
}

// Round 6
// 202.172 us; speedup vs baseline: 1.0055x; 1.0055x over previous
//
#include <hip/hip_runtime.h>
#include <cstddef>

#define SSM_N 64
#define SSM_H 256
#define SSM_B 8
#define SSM_L 1024
#define PADB  68    // LDS row stride (floats); 272B rows, 16B-aligned
#define KTP   1040  // K_T row stride in floats

// ---------- prep helpers ----------

// lane's full row r of a 64x64 LDS matrix into 64 regs (16 x b128; 8-way bank
// alias tolerated: 16 reads/matmul only)
__device__ __forceinline__ void load_row(const float* M, int r, float (&arow)[64])
{
    #pragma unroll
    for (int q = 0; q < 16; ++q) {
        const float4 v = *reinterpret_cast<const float4*>(M + r * PADB + 4 * q);
        arow[4*q+0] = v.x; arow[4*q+1] = v.y; arow[4*q+2] = v.z; arow[4*q+3] = v.w;
    }
}

// acc[0..7] += arow[t] * B[t][g8 .. g8+7].  B reads are wave-uniform float4
// broadcasts (g8 constant per wave) -> conflict-free.
__device__ __forceinline__ void mm_row8(const float (&arow)[64], const float* B,
                                        int g8, float (&acc)[8])
{
    #pragma unroll
    for (int t = 0; t < 64; ++t) {
        const float4 b0 = *reinterpret_cast<const float4*>(B + t * PADB + g8);
        const float4 b1 = *reinterpret_cast<const float4*>(B + t * PADB + g8 + 4);
        const float a = arow[t];
        acc[0] += a * b0.x; acc[1] += a * b0.y; acc[2] += a * b0.z; acc[3] += a * b0.w;
        acc[4] += a * b1.x; acc[5] += a * b1.y; acc[6] += a * b1.z; acc[7] += a * b1.w;
    }
}

// One block per channel h. 512 threads = 8 waves; lane r = tid&63 owns row r,
// wave w = tid>>6 owns cols [8w, 8w+8). Doubling ladder E_k = Ab^(2^k), k=0..9.
// __launch_bounds__(512, 2): VGPR cap 256 so arow[64] stays in registers
// (round-5 default heuristic capped at 68 VGPR -> 361 MB scratch spill traffic).
__global__ __launch_bounds__(512, 2) void ssm_prep_kernel(
    const float* __restrict__ As, const float* __restrict__ Bsin,
    const float* __restrict__ Csin, const float* __restrict__ logsteps,
    float* __restrict__ KTout)
{
    __shared__ __align__(16) float Ea[SSM_N * PADB];
    __shared__ __align__(16) float Eb[SSM_N * PADB];
    __shared__ __align__(16) float Cm[32 * PADB];
    __shared__ __align__(16) float Xm[32 * PADB];
    __shared__ float bvs[64];

    const int h   = blockIdx.x;
    const int tid = threadIdx.x;
    const int r   = tid & 63;
    const int w   = tid >> 6;
    const int g8  = w * 8;

    const float step = expf(logsteps[h]);
    const float s    = 0.5f * step;

    // ---- stage M = s*A (coalesced float4), Cs -> Cm row 0, b -> bvs ----
    #pragma unroll
    for (int ps = 0; ps < 2; ++ps) {
        const float4 v = *reinterpret_cast<const float4*>(
            As + (size_t)h * 4096 + 2048 * ps + 4 * tid);
        const int row = 32 * ps + (tid >> 4);
        const int col = (tid & 15) * 4;
        *reinterpret_cast<float4*>(Ea + row * PADB + col) =
            make_float4(s * v.x, s * v.y, s * v.z, s * v.w);
    }
    if (tid < 64)       Cm[tid]        = Csin[h * SSM_N + tid];
    else if (tid < 128) bvs[tid - 64]  = Bsin[h * SSM_N + tid - 64];
    __syncthreads();

    float arow[64];
    load_row(Ea, r, arow);                 // M row r (reused for both Neumann mms)
    float acc[8];

    // ---- T = M*M + M -> Eb ----
    #pragma unroll
    for (int j = 0; j < 8; ++j) acc[j] = arow[g8 + j];
    mm_row8(arow, Ea, g8, acc);
    *reinterpret_cast<float4*>(Eb + r * PADB + g8)     = make_float4(acc[0], acc[1], acc[2], acc[3]);
    *reinterpret_cast<float4*>(Eb + r * PADB + g8 + 4) = make_float4(acc[4], acc[5], acc[6], acc[7]);
    __syncthreads();

    // ---- S = M*T + M ; E0 = I + 2S -> Ea ----
    #pragma unroll
    for (int j = 0; j < 8; ++j) acc[j] = arow[g8 + j];
    mm_row8(arow, Eb, g8, acc);
    #pragma unroll
    for (int j = 0; j < 8; ++j)
        Ea[r * PADB + g8 + j] = 2.f * acc[j] + ((r == g8 + j) ? 1.f : 0.f);
    __syncthreads();

    // ---- ladder k = 0..9 ----
    float* Ecur = Ea;
    float* Enxt = Eb;
    #pragma unroll 1
    for (int k = 0; k < 10; ++k) {
        load_row(Ecur, r, arow);           // E_k row r

        if (k == 0 && w == 0) {
            // x0 = Bb = s*(b + E0 b)
            float a = 0.f;
            #pragma unroll
            for (int t = 0; t < 64; ++t) a += arow[t] * bvs[t];
            Xm[r] = s * (bvs[r] + a);
        }

        if (k <= 4) {
            // c-stage: c_{j+2^k} = c_j * E_k  (lane = output column r)
            const int nj = 1 << k;
            #pragma unroll
            for (int rep = 0; rep < 2; ++rep) {
                const int j = w + 8 * rep;
                if (j < nj) {
                    const float* crow = Cm + j * PADB;
                    float a = 0.f;
                    #pragma unroll
                    for (int t = 0; t < 64; ++t)
                        a += crow[t] * Ecur[t * PADB + r];
                    Cm[(j + nj) * PADB + r] = a;
                }
            }
        } else {
            // x-stage: x_{m+2^kx} = E_{5+kx} x_m  (lane = output row r)
            const int kx = k - 5;
            const int nm = 1 << kx;
            #pragma unroll
            for (int rep = 0; rep < 2; ++rep) {
                const int m = w + 8 * rep;
                if (m < nm) {
                    const float* xs = Xm + m * PADB;
                    float a = 0.f;
                    #pragma unroll
                    for (int t = 0; t < 64; ++t)
                        a += arow[t] * xs[t];
                    Xm[(m + nm) * PADB + r] = a;
                }
            }
        }

        if (k < 9) {
            #pragma unroll
            for (int j = 0; j < 8; ++j) acc[j] = 0.f;
            mm_row8(arow, Ecur, g8, acc);
            *reinterpret_cast<float4*>(Enxt + r * PADB + g8)     = make_float4(acc[0], acc[1], acc[2], acc[3]);
            *reinterpret_cast<float4*>(Enxt + r * PADB + g8 + 4) = make_float4(acc[4], acc[5], acc[6], acc[7]);
        }
        __syncthreads();
        float* tmp = Ecur; Ecur = Enxt; Enxt = tmp;
    }

    // ---- KT[h][32m + j] = dot(c_j, x_m)  (coalesced contiguous write) ----
    #pragma unroll
    for (int rep = 0; rep < 2; ++rep) {
        const int l = tid + 512 * rep;
        const int m = l >> 5, j = l & 31;
        const float4* cr = reinterpret_cast<const float4*>(Cm + j * PADB);
        const float4* xr = reinterpret_cast<const float4*>(Xm + m * PADB);
        float d = 0.f;
        #pragma unroll
        for (int i = 0; i < 16; ++i) {
            const float4 c4 = cr[i], x4 = xr[i];
            d += c4.x * x4.x + c4.y * x4.y + c4.z * x4.z + c4.w * x4.w;
        }
        KTout[(size_t)h * KTP + l] = d;
    }
}

// ---------- KT (H x KTP) -> K (L x H), 32x32 LDS tiles ----------
__global__ __launch_bounds__(256) void ssm_ktr_kernel(
    const float* __restrict__ KT, float* __restrict__ K)
{
    __shared__ float tile[32][33];
    const int l0 = (blockIdx.x & 31) * 32;
    const int h0 = (blockIdx.x >> 5) * 32;
    const int c  = threadIdx.x & 31;
    const int r0 = threadIdx.x >> 5;
    #pragma unroll
    for (int k = 0; k < 4; ++k)
        tile[r0 + 8 * k][c] = KT[(size_t)(h0 + r0 + 8 * k) * KTP + l0 + c];
    __syncthreads();
    #pragma unroll
    for (int k = 0; k < 4; ++k)
        K[(size_t)(l0 + r0 + 8 * k) * SSM_H + h0 + c] = tile[c][r0 + 8 * k];
}

// ---------- conv helpers ----------

__device__ __forceinline__ void ld8(float (&d)[8], const float* base)
{
    #pragma unroll
    for (int j = 0; j < 8; ++j) d[j] = base[j * SSM_H];
}

// acc[i] += K[dd] * W[7+i-dd], W = cur[0..7] ++ prv[0..6]
__device__ __forceinline__ void fma8(float (&acc)[8], const float (&kv)[8],
                                     const float (&cur)[8], const float (&prv)[8])
{
    #pragma unroll
    for (int dd = 0; dd < 8; ++dd) {
        const float k = kv[dd];
        #pragma unroll
        for (int i = 0; i < 8; ++i) {
            const int idx = 7 + i - dd;
            const float u = (idx < 8) ? cur[idx] : prv[idx - 8];
            acc[i] += k * u;
        }
    }
}

// Causal conv with DEPTH-2 prefetch. Chunk c (8 d-values) uses window slot
// (c&3) + prev slot; loads for chunk c+2 are issued during chunk c into slot
// ((c+2)&3). Main loop covers chunks 0..T-1 (T = t&~3, static slots); remainder
// T..t-1 is a copy-rotation; final chunk t reloads its 15 operands (slot-free).
// Dead prefetches past the end are clamped to valid addresses (values unused).
__global__ __launch_bounds__(256, 2) void ssm_conv_kernel(
    const float* __restrict__ U, const float* __restrict__ Kk,
    const float* __restrict__ Ds, float* __restrict__ Y)
{
    const int h = threadIdx.x;
    const int b = blockIdx.x & 7;            // XCD-pinned batch slice
    const int p = blockIdx.x >> 3;           // 0..63
    const float dh = Ds[h];
    const float* Ub = U + (size_t)b * SSM_L * SSM_H + h;
    float* Yb = Y + (size_t)b * SSM_L * SSM_H + h;

    #pragma unroll
    for (int half = 0; half < 2; ++half) {
        const int t  = half ? (127 - p) : p;
        const int l0 = t << 3;

        float acc[8];
        #pragma unroll
        for (int i = 0; i < 8; ++i) acc[i] = 0.f;

        if (t >= 1) {
            float w0[8], w1[8], w2[8], w3[8], k0[8], k1[8], k2[8], k3[8];

            // prologue: wcur(c)[j] = u[l0-8c-7+j]
            #pragma unroll
            for (int j = 0; j < 7; ++j) w3[j] = Ub[(l0 + 1 + j) * SSM_H]; // wcur(-1)
            w3[7] = 0.f;
            #pragma unroll
            for (int j = 0; j < 8; ++j) w0[j] = Ub[(l0 - 7 + j) * SSM_H]; // wcur(0)
            {
                const int o = (l0 >= 15) ? (l0 - 15) : 0;                 // wcur(1), dead if t==1
                ld8(w1, Ub + (size_t)o * SSM_H);
            }
            ld8(k0, Kk + h);
            ld8(k1, Kk + 8 * SSM_H + h);

            int woff = l0 - 23;    // base row of wcur(c+2), c=0
            int koff = 16;         // base d of k(c+2), c=0
            const int T = t & ~3;

            #pragma unroll 1
            for (int c = 0; c < T; c += 4) {
                // chunk c: cur w0, prv w3, k0; prefetch -> slot 2
                {
                    const int wo = (woff > 0) ? woff : 0;
                    ld8(w2, Ub + (size_t)wo * SSM_H);
                    ld8(k2, Kk + (size_t)koff * SSM_H + h);
                }
                fma8(acc, k0, w0, w3);
                woff -= 8; koff = (koff < 1016) ? koff + 8 : 1016;
                // chunk c+1: cur w1, prv w0, k1; prefetch -> slot 3
                {
                    const int wo = (woff > 0) ? woff : 0;
                    ld8(w3, Ub + (size_t)wo * SSM_H);
                    ld8(k3, Kk + (size_t)koff * SSM_H + h);
                }
                fma8(acc, k1, w1, w0);
                woff -= 8; koff = (koff < 1016) ? koff + 8 : 1016;
                // chunk c+2: cur w2, prv w1, k2; prefetch -> slot 0
                {
                    const int wo = (woff > 0) ? woff : 0;
                    ld8(w0, Ub + (size_t)wo * SSM_H);
                    ld8(k0, Kk + (size_t)koff * SSM_H + h);
                }
                fma8(acc, k2, w2, w1);
                woff -= 8; koff = (koff < 1016) ? koff + 8 : 1016;
                // chunk c+3: cur w3, prv w2, k3; prefetch -> slot 1
                {
                    const int wo = (woff > 0) ? woff : 0;
                    ld8(w1, Ub + (size_t)wo * SSM_H);
                    ld8(k1, Kk + (size_t)koff * SSM_H + h);
                }
                fma8(acc, k3, w3, w2);
                woff -= 8; koff = (koff < 1016) ? koff + 8 : 1016;
            }

            // remainder chunks c = T..t-1. Entry state (T = 0 mod 4):
            // cur = w0 = wcur(T), prv = w3 = wcur(T-1), k0 = k(T);
            // next-arrived: w1 = wcur(T+1), k1 = k(T+1).
            #pragma unroll 1
            for (int c = T; c < t; ++c) {
                float wnn[8], knn[8];
                const int wo = (woff > 0) ? woff : 0;
                ld8(wnn, Ub + (size_t)wo * SSM_H);
                ld8(knn, Kk + (size_t)koff * SSM_H + h);
                fma8(acc, k0, w0, w3);
                #pragma unroll
                for (int j = 0; j < 8; ++j) {
                    w3[j] = w0[j]; w0[j] = w1[j]; w1[j] = wnn[j];
                    k0[j] = k1[j]; k1[j] = knn[j];
                }
                woff -= 8; koff = (koff < 1016) ? koff + 8 : 1016;
            }
        }

        // final chunk c = t (slot-independent: reload its 15 operands).
        // W = [0 x7, u[0]] ++ u[1..7]
        {
            float kt[8], ur[7];
            #pragma unroll
            for (int j = 0; j < 8; ++j) kt[j] = Kk[(8 * t + j) * SSM_H + h];
            #pragma unroll
            for (int j = 0; j < 7; ++j) ur[j] = Ub[(1 + j) * SSM_H];
            const float uz = Ub[0];
            #pragma unroll
            for (int dd = 0; dd < 8; ++dd) {
                const float k = kt[dd];
                #pragma unroll
                for (int i = 0; i < 8; ++i) {
                    const int idx = 7 + i - dd;
                    if (idx == 7)      acc[i] += k * uz;
                    else if (idx > 7)  acc[i] += k * ur[idx - 8];
                }
            }
        }

        #pragma unroll
        for (int i = 0; i < 8; ++i)
            Yb[(l0 + i) * SSM_H] = acc[i] + dh * Ub[(l0 + i) * SSM_H];
    }
}

extern "C" void kernel_launch(void* const* d_in, const int* in_sizes, int n_in,
                              void* d_out, int out_size, void* d_ws, size_t ws_size,
                              hipStream_t stream)
{
    const float* inp    = (const float*)d_in[0];  // (B,L,H)
    const float* As     = (const float*)d_in[1];  // (H,N,N)
    const float* Bsin   = (const float*)d_in[2];  // (H,N,1)
    const float* Csin   = (const float*)d_in[3];  // (H,1,N)
    const float* Dsin   = (const float*)d_in[4];  // (H,)
    const float* lsteps = (const float*)d_in[5];  // (H,)
    float* Y    = (float*)d_out;                  // (B,L,H)
    // KT staged in d_out head (consumed by ktr before conv overwrites with Y);
    // K (L,H) in 1MB of d_ws.
    float* KT   = (float*)d_out;
    float* Kbuf = (float*)d_ws;

    ssm_prep_kernel<<<dim3(SSM_H), dim3(512), 0, stream>>>(As, Bsin, Csin, lsteps, KT);
    ssm_ktr_kernel<<<dim3(256), dim3(256), 0, stream>>>(KT, Kbuf);
    ssm_conv_kernel<<<dim3(512), dim3(256), 0, stream>>>(inp, Kbuf, Dsin, Y);
}